// Round 1
// baseline (261.650 us; speedup 1.0000x reference)
//
#include <hip/hip_runtime.h>

// MRGCO: real-FFT tensor-product RGCN layer.
// real(fft) along k (len 8) = rank-5 cosine transform (j and 8-j rows equal);
// the ifft->fft round-trip between the two tensor products cancels exactly.
//
// Pipeline (3 kernels):
//   k_pre  : A->Af (5 planes, bf16 swizzled), X->Xft (LDS transpose, swizzled),
//            W->Wbig[(h*8+k)][(j*256+h')] = c_jk*sc_j*F_j(W[h'][h])  (combine
//            coefficients folded into the weight -> gemm2+combine become 1 GEMM)
//   gemm1  : C1[n][(j,h')] = Af_j @ Xft_j  (batched over j, shared 2048x1280
//            swizzled bf16 output)
//   gemm2b : out[n][(h,k)] = C1 @ Wbig^T   (K=1280, N=2048, grid 16x16 = 256
//            blocks = 1/CU; writes final out directly, no combine kernel)
//
// Swizzle: logical (row r, col c) of a K-contiguous operand stored at
//   r*K + (c&~63) + ((((c>>3)&7) ^ (r&7))<<3) + (c&7)
// so a LINEAR wave-uniform global_load_lds DMA lands tiles in LDS already
// bank-swizzled; ds_read_b128 fragment reads stay conflict-free.
// GEMM K-loop: double-buffered LDS, raw s_barrier + manual s_waitcnt vmcnt(8)
// so the next tile's DMA stays in flight across the barrier (m139/AITER style).

typedef __bf16 bf16_t;
typedef __bf16 bf16x2 __attribute__((ext_vector_type(2)));
typedef __bf16 bf16x8 __attribute__((ext_vector_type(8)));
typedef float f32x4 __attribute__((ext_vector_type(4)));

#define R2C 0.70710678118654752f

__device__ __forceinline__ size_t swz(int r, int c, int K) {
  return (size_t)r * K + (c & ~63) + ((((c >> 3) & 7) ^ (r & 7)) << 3) + (c & 7);
}

__device__ __forceinline__ void async_cp16(const void* g, void* l) {
  __builtin_amdgcn_global_load_lds((const __attribute__((address_space(1))) char*)g,
                                   (__attribute__((address_space(3))) char*)l,
                                   16, 0, 0);
}

__device__ __forceinline__ void fwd5(const float x[8], float F[5]) {
  float s04 = x[0] + x[4], d04 = x[0] - x[4];
  float s26 = x[2] + x[6];
  float s15 = x[1] + x[5], s37 = x[3] + x[7];
  float t = (x[1] + x[7]) - (x[3] + x[5]);
  float e = s04 + s26, o = s15 + s37;
  F[0] = e + o;
  F[1] = d04 + R2C * t;
  F[2] = s04 - s26;
  F[3] = d04 - R2C * t;
  F[4] = e - o;
}

// Fused input transforms. blocks [0,8192): A ; [8192,8448): X ; [8448,8704): W.
__global__ __launch_bounds__(256) void k_pre(const float* __restrict__ X,
                                             const float* __restrict__ A,
                                             const float* __restrict__ W,
                                             bf16_t* __restrict__ Xft,
                                             bf16_t* __restrict__ Af,
                                             bf16_t* __restrict__ Wbig) {
  __shared__ bf16_t tx[40][256];  // X transpose staging: [j*8+h][m]
  int b = blockIdx.x;
  if (b < 8192) {
    // Af[j][n][m] swizzled; two consecutive m per thread (coalesced r/w)
    size_t t = (size_t)b * 256 + threadIdx.x;
    size_t idx = t * 2;  // n*2048 + m
    int n = (int)(idx >> 11), m = (int)(idx & 2047);
    const float4* p = (const float4*)(A + idx * 8);
    float4 q0 = p[0], q1 = p[1], q2 = p[2], q3 = p[3];
    float x0[8] = {q0.x, q0.y, q0.z, q0.w, q1.x, q1.y, q1.z, q1.w};
    float x1[8] = {q2.x, q2.y, q2.z, q2.w, q3.x, q3.y, q3.z, q3.w};
    float F0[5], F1[5];
    fwd5(x0, F0);
    fwd5(x1, F1);
    size_t pos = swz(n, m, 2048);
#pragma unroll
    for (int j = 0; j < 5; j++) {
      bf16x2 v = {(bf16_t)F0[j], (bf16_t)F1[j]};
      *(bf16x2*)(Af + (size_t)j * 4194304 + pos) = v;
    }
  } else if (b < 8448) {
    // Xft[j][h][m]: tile 256 m x 8 h. Coalesced reads -> LDS -> full 16B
    // swizzled chunk writes (no partial-line scatter).
    int bx = b - 8192;
    int m0 = (bx & 7) * 256, h0 = (bx >> 3) * 8;
    int t = threadIdx.x;
    const float4* p = (const float4*)(X + (((size_t)(m0 + t) * 256) + h0) * 8);
#pragma unroll
    for (int h = 0; h < 8; h++) {
      float4 a = p[2 * h], bb = p[2 * h + 1];
      float x[8] = {a.x, a.y, a.z, a.w, bb.x, bb.y, bb.z, bb.w};
      float F[5];
      fwd5(x, F);
#pragma unroll
      for (int j = 0; j < 5; j++) tx[j * 8 + h][t] = (bf16_t)F[j];
    }
    __syncthreads();
#pragma unroll
    for (int it = 0; it < 5; it++) {
      int slot = it * 256 + t;
      int row = slot >> 5, ch = slot & 31;
      int j = row >> 3, hl = row & 7;
      int h = h0 + hl;
      size_t gpos = (size_t)j * 524288 + (size_t)h * 2048 + m0 +
                    ((ch & ~7) << 3) + (((ch & 7) ^ (h & 7)) << 3);
      *(uint4*)(Xft + gpos) = *(const uint4*)(&tx[row][ch * 8]);
    }
  } else {
    // Wbig[(h*8+k)][(j*256+h')] = cos(2*pi*j*k/8) * sc_j * F_j(W[h'][h][:]),
    // swizzled for K=1280. Folds the ifft combine into the second GEMM's B.
    int h = b - 8448;
    int hp = threadIdx.x;
    const float4* p = (const float4*)(W + ((size_t)hp * 256 + h) * 8);
    float4 a = p[0], bb = p[1];
    float x[8] = {a.x, a.y, a.z, a.w, bb.x, bb.y, bb.z, bb.w};
    float F[5];
    fwd5(x, F);
    const float sc[5] = {0.125f, 0.25f, 0.25f, 0.25f, 0.125f};
    const float CK[8][5] = {
        {1.f, 1.f, 1.f, 1.f, 1.f},
        {1.f, R2C, 0.f, -R2C, -1.f},
        {1.f, 0.f, -1.f, 0.f, 1.f},
        {1.f, -R2C, 0.f, R2C, -1.f},
        {1.f, -1.f, 1.f, -1.f, 1.f},
        {1.f, -R2C, 0.f, R2C, -1.f},
        {1.f, 0.f, -1.f, 0.f, 1.f},
        {1.f, R2C, 0.f, -R2C, -1.f}};
#pragma unroll
    for (int k = 0; k < 8; k++) {
      int c = h * 8 + k;  // output column (row of B-operand)
      size_t base = (size_t)c * 1280 + (hp & ~63) +
                    ((((hp >> 3) & 7) ^ (c & 7)) << 3) + (hp & 7);
#pragma unroll
      for (int j = 0; j < 5; j++)
        Wbig[base + (size_t)j * 256] = (bf16_t)(F[j] * sc[j] * CK[k][j]);
    }
  }
}

// Batched bf16 GEMM, 128x128 tile, BK=64, 4 waves (64x64 each), 16x16x32 MFMA.
// Swizzled operands; global_load_lds width-16 staging, double-buffered LDS with
// raw s_barrier + manual vmcnt(8) so prefetch stays in flight across barriers.
// A rows stride = K; B rows (= output cols) stride = K; C row stride = ldc.
template <typename OutT, bool SWZ_OUT>
__global__ __launch_bounds__(256) void gemm_lds(const bf16_t* __restrict__ A,
                                                const bf16_t* __restrict__ B,
                                                OutT* __restrict__ C, int K,
                                                int ldc, size_t ap, size_t bp,
                                                size_t cp) {
  __shared__ bf16_t sm[4 * 8192];  // [A0|A1|B0|B1], 64KB
  const int j = blockIdx.z;
  const bf16_t* Aj = A + (size_t)j * ap;
  const bf16_t* Bj = B + (size_t)j * bp;
  OutT* Cj = C + (size_t)j * cp;
  const int n0 = blockIdx.x * 128, h0 = blockIdx.y * 128;
  const int tid = threadIdx.x;
  const int wv = tid >> 6, ln = tid & 63;
  const int quad = ln >> 4, l16 = ln & 15;
  const int wn = (wv & 1) * 64, wh = (wv >> 1) * 64;

  const bf16_t* ga[4];
  const bf16_t* gb[4];
  int lo[4];  // element offset inside one 8192-elem buffer (wave-uniform)
#pragma unroll
  for (int s = 0; s < 4; s++) {
    int slot = s * 256 + tid;
    int row = slot >> 3, c16 = slot & 7;
    ga[s] = Aj + (size_t)(n0 + row) * K + c16 * 8;
    gb[s] = Bj + (size_t)(h0 + row) * K + c16 * 8;
    lo[s] = (s * 256 + wv * 64) * 8;
  }

  // prologue: tile 0 -> buffer 0
#pragma unroll
  for (int s = 0; s < 4; s++) {
    async_cp16(ga[s], sm + lo[s]);
    async_cp16(gb[s], sm + 16384 + lo[s]);
  }

  f32x4 acc[4][4] = {};
  for (int kk = 0; kk < K; kk += 64) {
    int p = (kk >> 6) & 1;
    if (kk + 64 < K) {
#pragma unroll
      for (int s = 0; s < 4; s++) {
        async_cp16(ga[s] + kk + 64, sm + (p ^ 1) * 8192 + lo[s]);
        async_cp16(gb[s] + kk + 64, sm + 16384 + (p ^ 1) * 8192 + lo[s]);
      }
      __builtin_amdgcn_s_waitcnt(0xF78);  // vmcnt(8): tile kk landed
    } else {
      __builtin_amdgcn_s_waitcnt(0xF70);  // vmcnt(0): last tile landed
    }
    __builtin_amdgcn_s_barrier();
    const bf16_t* Asp = sm + p * 8192;
    const bf16_t* Bsp = sm + 16384 + p * 8192;
#pragma unroll
    for (int kh = 0; kh < 2; kh++) {
      bf16x8 af[4], bfr[4];
      int c16 = kh * 4 + quad;
#pragma unroll
      for (int i = 0; i < 4; i++) {
        int ra = wn + i * 16 + l16;
        int rb = wh + i * 16 + l16;
        af[i] = *(const bf16x8*)(Asp + ra * 64 + ((c16 ^ (ra & 7)) << 3));
        bfr[i] = *(const bf16x8*)(Bsp + rb * 64 + ((c16 ^ (rb & 7)) << 3));
      }
#pragma unroll
      for (int i = 0; i < 4; i++)
#pragma unroll
        for (int t = 0; t < 4; t++)
          acc[i][t] = __builtin_amdgcn_mfma_f32_16x16x32_bf16(af[i], bfr[t],
                                                              acc[i][t], 0, 0, 0);
    }
    __builtin_amdgcn_s_barrier();  // protect buffer p^1 before next-iter DMA
  }
  // C/D layout: col = lane&15, row = quad*4 + reg
#pragma unroll
  for (int i = 0; i < 4; i++) {
#pragma unroll
    for (int t = 0; t < 4; t++) {
      int hc = h0 + wh + t * 16 + l16;
#pragma unroll
      for (int rg = 0; rg < 4; rg++) {
        int nr = n0 + wn + i * 16 + quad * 4 + rg;
        size_t off = SWZ_OUT ? swz(nr, hc, ldc) : (size_t)nr * ldc + hc;
        Cj[off] = (OutT)acc[i][t][rg];
      }
    }
  }
}

extern "C" void kernel_launch(void* const* d_in, const int* in_sizes, int n_in,
                              void* d_out, int out_size, void* d_ws, size_t ws_size,
                              hipStream_t stream) {
  const float* X = (const float*)d_in[0];   // (2048,256,8)
  const float* A = (const float*)d_in[1];   // (2048,2048,8)
  const float* W = (const float*)d_in[2];   // (256,256,8)
  float* out = (float*)d_out;               // (2048,256,8) == [n][h*8+k]
  char* ws = (char*)d_ws;

  bf16_t* Af   = (bf16_t*)(ws);              // 5*2048*2048*2 = 41943040
  bf16_t* Xft  = (bf16_t*)(ws + 41943040);   // 5*256*2048*2  =  5242880
  bf16_t* Wbig = (bf16_t*)(ws + 47185920);   // 2048*1280*2   =  5242880
  bf16_t* C1   = (bf16_t*)(ws + 52428800);   // 2048*1280*2   =  5242880
                                             // total 57671680 B

  k_pre<<<dim3(8704), 256, 0, stream>>>(X, A, W, Xft, Af, Wbig);
  // C1[n][(j,h')] = Af_j @ Xft_j ; output cols j*256+hc of a 2048x1280 matrix
  gemm_lds<bf16_t, true><<<dim3(16, 2, 5), 256, 0, stream>>>(
      Af, Xft, C1, 2048, 1280, (size_t)4194304, (size_t)524288, (size_t)256);
  // out[n][(h,k)] = C1 @ Wbig^T ; K=1280, grid 16x16 = 256 blocks = 1/CU
  gemm_lds<float, false><<<dim3(16, 16, 1), 256, 0, stream>>>(
      C1, Wbig, out, 1280, 2048, (size_t)0, (size_t)0, (size_t)0);
}

// Round 3
// 256.827 us; speedup vs baseline: 1.0188x; 1.0188x over previous
//
#include <hip/hip_runtime.h>

// MRGCO: real-FFT tensor-product RGCN layer.  (RERUN of round-2 source —
// bench infra failed twice with no verdict; kernel audited for hang causes,
// none found; resubmitting unchanged to preserve the A/B vs round 0.)
//
// real(fft) along k (len 8) = rank-5 cosine transform (j and 8-j rows equal);
// the ifft->fft round-trip between the two tensor products cancels exactly.
//
// Pipeline (4 kernels, block-diagonal form — 1.34 GF second GEMM):
//   k_pre    : A->Af (5 planes, bf16 swizzled), X->Xft (LDS transpose), W->Wft
//   gemm_ring: C1_j = Af_j @ Xft_j   (K=2048, 4-deep LDS ring, counted vmcnt)
//   gemm_flat: C2_j = C1_j @ Wft_j   (K=256 staged whole, single barrier)
//   k_combine: out[n][h][k] = sum_j c_jk * C2_j[n][h]
//
// Swizzle: logical (row r, col c) of a K-contiguous operand stored at
//   r*K + (c&~63) + ((((c>>3)&7) ^ (r&7))<<3) + (c&7)
// so a LINEAR wave-uniform global_load_lds DMA lands tiles in LDS already
// bank-swizzled; ds_read_b128 fragment reads stay conflict-free.
//
// gemm_ring K-loop: 4 LDS buffers (128 KB), prefetch 3 tiles ahead, raw
// s_barrier + counted s_waitcnt vmcnt(24/16/8/0) so three tiles' DMA stays in
// flight across barriers — at 1 block/CU (grid 160 < 256 CUs) there is no
// inter-block latency hiding, so the in-flight depth must cover L3/HBM latency.

typedef __bf16 bf16_t;
typedef __bf16 bf16x2 __attribute__((ext_vector_type(2)));
typedef __bf16 bf16x8 __attribute__((ext_vector_type(8)));
typedef float f32x4 __attribute__((ext_vector_type(4)));

#define R2C 0.70710678118654752f

__device__ __forceinline__ size_t swz(int r, int c, int K) {
  return (size_t)r * K + (c & ~63) + ((((c >> 3) & 7) ^ (r & 7)) << 3) + (c & 7);
}

__device__ __forceinline__ void async_cp16(const void* g, void* l) {
  __builtin_amdgcn_global_load_lds((const __attribute__((address_space(1))) char*)g,
                                   (__attribute__((address_space(3))) char*)l,
                                   16, 0, 0);
}

__device__ __forceinline__ void fwd5(const float x[8], float F[5]) {
  float s04 = x[0] + x[4], d04 = x[0] - x[4];
  float s26 = x[2] + x[6];
  float s15 = x[1] + x[5], s37 = x[3] + x[7];
  float t = (x[1] + x[7]) - (x[3] + x[5]);
  float e = s04 + s26, o = s15 + s37;
  F[0] = e + o;
  F[1] = d04 + R2C * t;
  F[2] = s04 - s26;
  F[3] = d04 - R2C * t;
  F[4] = e - o;
}

// Fused input transforms. blocks [0,8192): A ; [8192,8448): X ; [8448,8704): W.
__global__ __launch_bounds__(256) void k_pre(const float* __restrict__ X,
                                             const float* __restrict__ A,
                                             const float* __restrict__ W,
                                             bf16_t* __restrict__ Xft,
                                             bf16_t* __restrict__ Af,
                                             bf16_t* __restrict__ Wft) {
  __shared__ bf16_t tx[40][256];  // X transpose staging: [j*8+h][m]
  int b = blockIdx.x;
  if (b < 8192) {
    // Af[j][n][m] swizzled; two consecutive m per thread (coalesced r/w)
    size_t t = (size_t)b * 256 + threadIdx.x;
    size_t idx = t * 2;  // n*2048 + m
    int n = (int)(idx >> 11), m = (int)(idx & 2047);
    const float4* p = (const float4*)(A + idx * 8);
    float4 q0 = p[0], q1 = p[1], q2 = p[2], q3 = p[3];
    float x0[8] = {q0.x, q0.y, q0.z, q0.w, q1.x, q1.y, q1.z, q1.w};
    float x1[8] = {q2.x, q2.y, q2.z, q2.w, q3.x, q3.y, q3.z, q3.w};
    float F0[5], F1[5];
    fwd5(x0, F0);
    fwd5(x1, F1);
    size_t pos = swz(n, m, 2048);
#pragma unroll
    for (int j = 0; j < 5; j++) {
      bf16x2 v = {(bf16_t)F0[j], (bf16_t)F1[j]};
      *(bf16x2*)(Af + (size_t)j * 4194304 + pos) = v;
    }
  } else if (b < 8448) {
    // Xft[j][h][m]: tile 256 m x 8 h. Coalesced reads -> LDS -> full 16B
    // swizzled chunk writes (no partial-line scatter).
    int bx = b - 8192;
    int m0 = (bx & 7) * 256, h0 = (bx >> 3) * 8;
    int t = threadIdx.x;
    const float4* p = (const float4*)(X + (((size_t)(m0 + t) * 256) + h0) * 8);
#pragma unroll
    for (int h = 0; h < 8; h++) {
      float4 a = p[2 * h], bb = p[2 * h + 1];
      float x[8] = {a.x, a.y, a.z, a.w, bb.x, bb.y, bb.z, bb.w};
      float F[5];
      fwd5(x, F);
#pragma unroll
      for (int j = 0; j < 5; j++) tx[j * 8 + h][t] = (bf16_t)F[j];
    }
    __syncthreads();
#pragma unroll
    for (int it = 0; it < 5; it++) {
      int slot = it * 256 + t;
      int row = slot >> 5, ch = slot & 31;
      int j = row >> 3, hl = row & 7;
      int h = h0 + hl;
      size_t gpos = (size_t)j * 524288 + (size_t)h * 2048 + m0 +
                    ((ch & ~7) << 3) + (((ch & 7) ^ (h & 7)) << 3);
      *(uint4*)(Xft + gpos) = *(const uint4*)(&tx[row][ch * 8]);
    }
  } else {
    // Wft[j][h][h'] = s_j * sum_k W[h'][h][k] c_jk, swizzled (tiny)
    int h = b - 8448;
    int hp = threadIdx.x;
    const float4* p = (const float4*)(W + ((size_t)hp * 256 + h) * 8);
    float4 a = p[0], bb = p[1];
    float x[8] = {a.x, a.y, a.z, a.w, bb.x, bb.y, bb.z, bb.w};
    float F[5];
    fwd5(x, F);
    const float sc[5] = {0.125f, 0.25f, 0.25f, 0.25f, 0.125f};
    size_t pos = swz(h, hp, 256);
#pragma unroll
    for (int j = 0; j < 5; j++)
      Wft[(size_t)j * 65536 + pos] = (bf16_t)(F[j] * sc[j]);
  }
}

// Batched bf16 GEMM, 128x128 tile, BK=64, 4 waves (64x64 each), 16x16x32 MFMA.
// 4-deep LDS ring (128 KB): prefetch 3 tiles ahead, counted vmcnt so loads
// have 3 compute-iterations to land. Swizzled bf16 output, ldc=256, batch z.
__global__ __launch_bounds__(256) void gemm_ring(const bf16_t* __restrict__ A,
                                                 const bf16_t* __restrict__ B,
                                                 bf16_t* __restrict__ C, int K,
                                                 size_t ap, size_t bp, size_t cp) {
  __shared__ bf16_t sm[65536];  // A ring: 4 x 8192 | B ring at +32768: 4 x 8192
  const int j = blockIdx.z;
  const bf16_t* Aj = A + (size_t)j * ap;
  const bf16_t* Bj = B + (size_t)j * bp;
  bf16_t* Cj = C + (size_t)j * cp;
  const int n0 = blockIdx.x * 128, h0 = blockIdx.y * 128;
  const int tid = threadIdx.x;
  const int wv = tid >> 6, ln = tid & 63;
  const int quad = ln >> 4, l16 = ln & 15;
  const int wn = (wv & 1) * 64, wh = (wv >> 1) * 64;

  const bf16_t* ga[4];
  const bf16_t* gb[4];
  int lo[4];  // element offset inside one 8192-elem buffer (wave-uniform)
#pragma unroll
  for (int s = 0; s < 4; s++) {
    int slot = s * 256 + tid;
    int row = slot >> 3, c16 = slot & 7;
    ga[s] = Aj + (size_t)(n0 + row) * K + c16 * 8;
    gb[s] = Bj + (size_t)(h0 + row) * K + c16 * 8;
    lo[s] = (s * 256 + wv * 64) * 8;
  }

  const int T = K >> 6;  // assumes T >= 4
  // prologue: tiles 0,1,2 -> buffers 0,1,2 (24 loads in flight)
#pragma unroll
  for (int i = 0; i < 3; i++) {
#pragma unroll
    for (int s = 0; s < 4; s++) {
      async_cp16(ga[s] + i * 64, sm + i * 8192 + lo[s]);
      async_cp16(gb[s] + i * 64, sm + 32768 + i * 8192 + lo[s]);
    }
  }

  f32x4 acc[4][4] = {};
  for (int t = 0; t < T; t++) {
    int b = t & 3;
    if (t + 3 < T) {
      int nb = (t + 3) & 3;
#pragma unroll
      for (int s = 0; s < 4; s++) {
        async_cp16(ga[s] + (t + 3) * 64, sm + nb * 8192 + lo[s]);
        async_cp16(gb[s] + (t + 3) * 64, sm + 32768 + nb * 8192 + lo[s]);
      }
      __builtin_amdgcn_s_waitcnt(0x4F78);  // vmcnt(24): tile t landed
    } else if (t + 2 < T) {
      __builtin_amdgcn_s_waitcnt(0x4F70);  // vmcnt(16)
    } else if (t + 1 < T) {
      __builtin_amdgcn_s_waitcnt(0xF78);   // vmcnt(8)
    } else {
      __builtin_amdgcn_s_waitcnt(0xF70);   // vmcnt(0)
    }
    __builtin_amdgcn_s_barrier();
    const bf16_t* Asp = sm + b * 8192;
    const bf16_t* Bsp = sm + 32768 + b * 8192;
#pragma unroll
    for (int kh = 0; kh < 2; kh++) {
      bf16x8 af[4], bfr[4];
      int c16 = kh * 4 + quad;
#pragma unroll
      for (int i = 0; i < 4; i++) {
        int ra = wn + i * 16 + l16;
        int rb = wh + i * 16 + l16;
        af[i] = *(const bf16x8*)(Asp + ra * 64 + ((c16 ^ (ra & 7)) << 3));
        bfr[i] = *(const bf16x8*)(Bsp + rb * 64 + ((c16 ^ (rb & 7)) << 3));
      }
#pragma unroll
      for (int i = 0; i < 4; i++)
#pragma unroll
        for (int t2 = 0; t2 < 4; t2++)
          acc[i][t2] = __builtin_amdgcn_mfma_f32_16x16x32_bf16(af[i], bfr[t2],
                                                               acc[i][t2], 0, 0, 0);
    }
    __builtin_amdgcn_s_barrier();  // protect buffer (t+4)&3 before next issue
  }
  // C/D layout: col = lane&15, row = quad*4 + reg ; swizzled bf16, ldc=256
#pragma unroll
  for (int i = 0; i < 4; i++) {
#pragma unroll
    for (int t = 0; t < 4; t++) {
      int hc = h0 + wh + t * 16 + l16;
#pragma unroll
      for (int rg = 0; rg < 4; rg++) {
        int nr = n0 + wn + i * 16 + quad * 4 + rg;
        Cj[swz(nr, hc, 256)] = (bf16_t)acc[i][t][rg];
      }
    }
  }
}

// Second tensor-product GEMM: K=256 staged in ONE shot (A-tile 128x256 +
// B-tile 128x256 = 128 KB LDS, 32 DMAs in flight, single vmcnt(0)+barrier).
// A = C1_j (2048x256 swizzled), B = Wft_j (256x256 swizzled), C = C2_j f32.
__global__ __launch_bounds__(256) void gemm_flat(const bf16_t* __restrict__ A,
                                                 const bf16_t* __restrict__ B,
                                                 float* __restrict__ C) {
  __shared__ bf16_t sm[65536];  // A [128][256] | B [128][256] at +32768
  const int j = blockIdx.z;
  const bf16_t* Aj = A + (size_t)j * 524288;
  const bf16_t* Bj = B + (size_t)j * 65536;
  float* Cj = C + (size_t)j * 524288;
  const int n0 = blockIdx.x * 128, h0 = blockIdx.y * 128;
  const int tid = threadIdx.x;
  const int wv = tid >> 6, ln = tid & 63;
  const int quad = ln >> 4, l16 = ln & 15;
  const int wn = (wv & 1) * 64, wh = (wv >> 1) * 64;

  // stage whole K: 16 slots A + 16 slots B, 16B each
#pragma unroll
  for (int s = 0; s < 16; s++) {
    int st = s * 256 + tid;
    int row = st >> 5, c = st & 31;
    int lo = (s * 256 + wv * 64) * 8;  // wave-uniform part; HW adds lane*16B
    async_cp16(Aj + (size_t)(n0 + row) * 256 + c * 8, sm + lo);
    async_cp16(Bj + (size_t)(h0 + row) * 256 + c * 8, sm + 32768 + lo);
  }
  __builtin_amdgcn_s_waitcnt(0xF70);  // vmcnt(0)
  __builtin_amdgcn_s_barrier();

  f32x4 acc[4][4] = {};
#pragma unroll
  for (int kh = 0; kh < 8; kh++) {
    bf16x8 af[4], bfr[4];
    int c16 = kh * 4 + quad;           // 8-col group 0..31
    int cb = (c16 & ~7) << 3;          // 64-col block byte-group base
#pragma unroll
    for (int i = 0; i < 4; i++) {
      int ra = wn + i * 16 + l16;
      int rb = wh + i * 16 + l16;
      af[i] = *(const bf16x8*)(sm + ra * 256 + cb + (((c16 & 7) ^ (ra & 7)) << 3));
      bfr[i] = *(const bf16x8*)(sm + 32768 + rb * 256 + cb +
                                (((c16 & 7) ^ (rb & 7)) << 3));
    }
#pragma unroll
    for (int i = 0; i < 4; i++)
#pragma unroll
      for (int t = 0; t < 4; t++)
        acc[i][t] = __builtin_amdgcn_mfma_f32_16x16x32_bf16(af[i], bfr[t],
                                                            acc[i][t], 0, 0, 0);
  }
  // C/D layout: col = lane&15, row = quad*4 + reg ; f32, row-major ldc=256
#pragma unroll
  for (int i = 0; i < 4; i++) {
#pragma unroll
    for (int t = 0; t < 4; t++) {
      int hc = h0 + wh + t * 16 + l16;
#pragma unroll
      for (int rg = 0; rg < 4; rg++) {
        int nr = n0 + wn + i * 16 + quad * 4 + rg;
        Cj[(size_t)nr * 256 + hc] = acc[i][t][rg];
      }
    }
  }
}

// out[n][h][k] = sum_j c_jk * C2_j[n][h]  (ifft scales folded into Wft)
__global__ __launch_bounds__(256) void k_combine(const float* __restrict__ C2,
                                                 float* __restrict__ out) {
  size_t idx = (size_t)blockIdx.x * 256 + threadIdx.x;
  float c0 = C2[idx];
  float c1 = C2[524288 + idx];
  float c2 = C2[2 * 524288 + idx];
  float c3 = C2[3 * 524288 + idx];
  float c4 = C2[4 * 524288 + idx];
  float o0 = c0 + c1 + c2 + c3 + c4;
  float o4 = c0 - c1 + c2 - c3 + c4;
  float o2 = c0 - c2 + c4;
  float rt = R2C * (c1 - c3);
  float o1 = c0 + rt - c4;
  float o3 = c0 - rt - c4;
  float4* op = (float4*)(out + idx * 8);
  op[0] = make_float4(o0, o1, o2, o3);
  op[1] = make_float4(o4, o3, o2, o1);
}

extern "C" void kernel_launch(void* const* d_in, const int* in_sizes, int n_in,
                              void* d_out, int out_size, void* d_ws, size_t ws_size,
                              hipStream_t stream) {
  const float* X = (const float*)d_in[0];   // (2048,256,8)
  const float* A = (const float*)d_in[1];   // (2048,2048,8)
  const float* W = (const float*)d_in[2];   // (256,256,8)
  float* out = (float*)d_out;               // (2048,256,8)
  char* ws = (char*)d_ws;

  bf16_t* Af  = (bf16_t*)(ws);              // 5*2048*2048*2 = 41943040
  bf16_t* Xft = (bf16_t*)(ws + 41943040);   // 5*256*2048*2  =  5242880
  bf16_t* Wft = (bf16_t*)(ws + 47185920);   // 5*256*256*2   =   655360
  bf16_t* C1  = (bf16_t*)(ws + 47841280);   // 5*2048*256*2  =  5242880
  float*  C2  = (float*) (ws + 53084160);   // 5*2048*256*4  = 10485760
                                            // total 63569920 B

  k_pre<<<dim3(8704), 256, 0, stream>>>(X, A, W, Xft, Af, Wft);
  gemm_ring<<<dim3(16, 2, 5), 256, 0, stream>>>(
      Af, Xft, C1, 2048, (size_t)4194304, (size_t)524288, (size_t)524288);
  gemm_flat<<<dim3(16, 2, 5), 256, 0, stream>>>(C1, Wft, C2);
  k_combine<<<dim3(2048), 256, 0, stream>>>(C2, out);
}

// Round 4
// 253.774 us; speedup vs baseline: 1.0310x; 1.0120x over previous
//
#include <hip/hip_runtime.h>

// MRGCO: real-FFT tensor-product RGCN layer.
// real(fft) along k (len 8) = rank-5 cosine transform (j and 8-j rows equal);
// the ifft->fft round-trip between the two tensor products cancels exactly.
//
// Pipeline (3 kernels):
//   k_pre    : A->Af (5 planes, bf16 swizzled, 16B stores), X->Xft, W->Wft
//   gemm_ring: C1_j = Af_j @ Xft_j   (K=2048, 4-deep LDS ring, counted vmcnt)
//   gemm_fc  : out[n][h][k] = sum_j c_jk * (C1_j @ Wft_j)[n][h]
//              (second tensor-product GEMM fused with the ifft combine:
//               j-loop inside the block, 5 k-accumulators in registers,
//               writes final out directly — C2 buffer + combine kernel gone)
//
// Swizzle: logical (row r, col c) of a K-contiguous operand stored at
//   r*K + (c&~63) + ((((c>>3)&7) ^ (r&7))<<3) + (c&7)
// so a LINEAR wave-uniform global_load_lds DMA lands tiles in LDS already
// bank-swizzled; ds_read_b128 fragment reads stay conflict-free.

typedef __bf16 bf16_t;
typedef __bf16 bf16x2 __attribute__((ext_vector_type(2)));
typedef __bf16 bf16x8 __attribute__((ext_vector_type(8)));
typedef float f32x4 __attribute__((ext_vector_type(4)));

#define R2C 0.70710678118654752f

__device__ __forceinline__ size_t swz(int r, int c, int K) {
  return (size_t)r * K + (c & ~63) + ((((c >> 3) & 7) ^ (r & 7)) << 3) + (c & 7);
}

__device__ __forceinline__ void async_cp16(const void* g, void* l) {
  __builtin_amdgcn_global_load_lds((const __attribute__((address_space(1))) char*)g,
                                   (__attribute__((address_space(3))) char*)l,
                                   16, 0, 0);
}

__device__ __forceinline__ void fwd5(const float x[8], float F[5]) {
  float s04 = x[0] + x[4], d04 = x[0] - x[4];
  float s26 = x[2] + x[6];
  float s15 = x[1] + x[5], s37 = x[3] + x[7];
  float t = (x[1] + x[7]) - (x[3] + x[5]);
  float e = s04 + s26, o = s15 + s37;
  F[0] = e + o;
  F[1] = d04 + R2C * t;
  F[2] = s04 - s26;
  F[3] = d04 - R2C * t;
  F[4] = e - o;
}

// Fused input transforms. blocks [0,2048): A ; [2048,2304): X ; [2304,2560): W.
__global__ __launch_bounds__(256) void k_pre(const float* __restrict__ X,
                                             const float* __restrict__ A,
                                             const float* __restrict__ W,
                                             bf16_t* __restrict__ Xft,
                                             bf16_t* __restrict__ Af,
                                             bf16_t* __restrict__ Wft) {
  __shared__ bf16_t tx[40][256];  // X transpose staging: [j*8+h][m]
  int b = blockIdx.x;
  if (b < 2048) {
    // Af[j][n][m] swizzled; 8 consecutive m per thread -> each plane write is
    // one full 16B swizzle chunk (bf16x8), perfectly coalesced.
    size_t t = (size_t)b * 256 + threadIdx.x;
    size_t idx = t * 8;  // n*2048 + m0, m0 multiple of 8
    int n = (int)(idx >> 11), m0 = (int)(idx & 2047);
    const float4* p = (const float4*)(A + idx * 8);
    float F[8][5];
#pragma unroll
    for (int u = 0; u < 8; u++) {
      float4 a = p[2 * u], bq = p[2 * u + 1];
      float x[8] = {a.x, a.y, a.z, a.w, bq.x, bq.y, bq.z, bq.w};
      fwd5(x, F[u]);
    }
    size_t pos = (size_t)n * 2048 + (m0 & ~63) +
                 ((((m0 >> 3) & 7) ^ (n & 7)) << 3);
#pragma unroll
    for (int j = 0; j < 5; j++) {
      bf16x8 v;
#pragma unroll
      for (int u = 0; u < 8; u++) v[u] = (bf16_t)F[u][j];
      *(bf16x8*)(Af + (size_t)j * 4194304 + pos) = v;
    }
  } else if (b < 2304) {
    // Xft[j][h][m]: tile 256 m x 8 h. Coalesced reads -> LDS -> full 16B
    // swizzled chunk writes (no partial-line scatter).
    int bx = b - 2048;
    int m0 = (bx & 7) * 256, h0 = (bx >> 3) * 8;
    int t = threadIdx.x;
    const float4* p = (const float4*)(X + (((size_t)(m0 + t) * 256) + h0) * 8);
#pragma unroll
    for (int h = 0; h < 8; h++) {
      float4 a = p[2 * h], bb = p[2 * h + 1];
      float x[8] = {a.x, a.y, a.z, a.w, bb.x, bb.y, bb.z, bb.w};
      float F[5];
      fwd5(x, F);
#pragma unroll
      for (int j = 0; j < 5; j++) tx[j * 8 + h][t] = (bf16_t)F[j];
    }
    __syncthreads();
#pragma unroll
    for (int it = 0; it < 5; it++) {
      int slot = it * 256 + t;
      int row = slot >> 5, ch = slot & 31;
      int j = row >> 3, hl = row & 7;
      int h = h0 + hl;
      size_t gpos = (size_t)j * 524288 + (size_t)h * 2048 + m0 +
                    ((ch & ~7) << 3) + (((ch & 7) ^ (h & 7)) << 3);
      *(uint4*)(Xft + gpos) = *(const uint4*)(&tx[row][ch * 8]);
    }
  } else {
    // Wft[j][h][h'] = s_j * sum_k W[h'][h][k] c_jk, swizzled (tiny)
    int h = b - 2304;
    int hp = threadIdx.x;
    const float4* p = (const float4*)(W + ((size_t)hp * 256 + h) * 8);
    float4 a = p[0], bb = p[1];
    float x[8] = {a.x, a.y, a.z, a.w, bb.x, bb.y, bb.z, bb.w};
    float F[5];
    fwd5(x, F);
    const float sc[5] = {0.125f, 0.25f, 0.25f, 0.25f, 0.125f};
    size_t pos = swz(h, hp, 256);
#pragma unroll
    for (int j = 0; j < 5; j++)
      Wft[(size_t)j * 65536 + pos] = (bf16_t)(F[j] * sc[j]);
  }
}

// Batched bf16 GEMM, 128x128 tile, BK=64, 4 waves (64x64 each), 16x16x32 MFMA.
// 4-deep LDS ring (128 KB): prefetch 3 tiles ahead, counted vmcnt so loads
// have 3 compute-iterations to land. Swizzled bf16 output, ldc=256, batch z.
__global__ __launch_bounds__(256) void gemm_ring(const bf16_t* __restrict__ A,
                                                 const bf16_t* __restrict__ B,
                                                 bf16_t* __restrict__ C, int K,
                                                 size_t ap, size_t bp, size_t cp) {
  __shared__ bf16_t sm[65536];  // A ring: 4 x 8192 | B ring at +32768: 4 x 8192
  const int j = blockIdx.z;
  const bf16_t* Aj = A + (size_t)j * ap;
  const bf16_t* Bj = B + (size_t)j * bp;
  bf16_t* Cj = C + (size_t)j * cp;
  const int n0 = blockIdx.x * 128, h0 = blockIdx.y * 128;
  const int tid = threadIdx.x;
  const int wv = tid >> 6, ln = tid & 63;
  const int quad = ln >> 4, l16 = ln & 15;
  const int wn = (wv & 1) * 64, wh = (wv >> 1) * 64;

  const bf16_t* ga[4];
  const bf16_t* gb[4];
  int lo[4];  // element offset inside one 8192-elem buffer (wave-uniform)
#pragma unroll
  for (int s = 0; s < 4; s++) {
    int slot = s * 256 + tid;
    int row = slot >> 3, c16 = slot & 7;
    ga[s] = Aj + (size_t)(n0 + row) * K + c16 * 8;
    gb[s] = Bj + (size_t)(h0 + row) * K + c16 * 8;
    lo[s] = (s * 256 + wv * 64) * 8;
  }

  const int T = K >> 6;  // assumes T >= 4
  // prologue: tiles 0,1,2 -> buffers 0,1,2 (24 loads in flight)
#pragma unroll
  for (int i = 0; i < 3; i++) {
#pragma unroll
    for (int s = 0; s < 4; s++) {
      async_cp16(ga[s] + i * 64, sm + i * 8192 + lo[s]);
      async_cp16(gb[s] + i * 64, sm + 32768 + i * 8192 + lo[s]);
    }
  }

  f32x4 acc[4][4] = {};
  for (int t = 0; t < T; t++) {
    int b = t & 3;
    if (t + 3 < T) {
      int nb = (t + 3) & 3;
#pragma unroll
      for (int s = 0; s < 4; s++) {
        async_cp16(ga[s] + (t + 3) * 64, sm + nb * 8192 + lo[s]);
        async_cp16(gb[s] + (t + 3) * 64, sm + 32768 + nb * 8192 + lo[s]);
      }
      __builtin_amdgcn_s_waitcnt(0x4F78);  // vmcnt(24): tile t landed
    } else if (t + 2 < T) {
      __builtin_amdgcn_s_waitcnt(0x4F70);  // vmcnt(16)
    } else if (t + 1 < T) {
      __builtin_amdgcn_s_waitcnt(0xF78);   // vmcnt(8)
    } else {
      __builtin_amdgcn_s_waitcnt(0xF70);   // vmcnt(0)
    }
    __builtin_amdgcn_s_barrier();
    const bf16_t* Asp = sm + b * 8192;
    const bf16_t* Bsp = sm + 32768 + b * 8192;
#pragma unroll
    for (int kh = 0; kh < 2; kh++) {
      bf16x8 af[4], bfr[4];
      int c16 = kh * 4 + quad;
#pragma unroll
      for (int i = 0; i < 4; i++) {
        int ra = wn + i * 16 + l16;
        int rb = wh + i * 16 + l16;
        af[i] = *(const bf16x8*)(Asp + ra * 64 + ((c16 ^ (ra & 7)) << 3));
        bfr[i] = *(const bf16x8*)(Bsp + rb * 64 + ((c16 ^ (rb & 7)) << 3));
      }
#pragma unroll
      for (int i = 0; i < 4; i++)
#pragma unroll
        for (int t2 = 0; t2 < 4; t2++)
          acc[i][t2] = __builtin_amdgcn_mfma_f32_16x16x32_bf16(af[i], bfr[t2],
                                                               acc[i][t2], 0, 0, 0);
    }
    __builtin_amdgcn_s_barrier();  // protect buffer (t+4)&3 before next issue
  }
  // C/D layout: col = lane&15, row = quad*4 + reg ; swizzled bf16, ldc=256
#pragma unroll
  for (int i = 0; i < 4; i++) {
#pragma unroll
    for (int t = 0; t < 4; t++) {
      int hc = h0 + wh + t * 16 + l16;
#pragma unroll
      for (int rg = 0; rg < 4; rg++) {
        int nr = n0 + wn + i * 16 + quad * 4 + rg;
        Cj[swz(nr, hc, 256)] = (bf16_t)acc[i][t][rg];
      }
    }
  }
}

// Fused second tensor-product + ifft combine.
// Block = 64x64 out tile (4 waves, 32x32 each). Loop j=0..4: stage C1_j/Wft_j
// 64x256 tiles (double-buffered, 16 DMAs/j, counted vmcnt(16)), MFMA K=256,
// fold C2_j into 5 k-accumulators with the cosine matrix, then write
// out[n][h][0..7] directly (k and 8-k mirror). Removes C2 + k_combine.
__global__ __launch_bounds__(256) void gemm_fc(const bf16_t* __restrict__ C1,
                                               const bf16_t* __restrict__ Wf,
                                               float* __restrict__ out) {
  __shared__ bf16_t sm[65536];  // buf p at p*32768: A[64][256] | B at +16384
  const int n0 = blockIdx.x * 64, h0 = blockIdx.y * 64;
  const int tid = threadIdx.x;
  const int wv = tid >> 6, ln = tid & 63;
  const int quad = ln >> 4, l16 = ln & 15;
  const int wn = (wv & 1) * 32, wh = (wv >> 1) * 32;

  const int srow = (tid >> 5), sc8 = (tid & 31) * 8;  // per-thread DMA coords
  const int lbase = wv * 512;                          // wave-uniform lds elems

  // stage j into buffer j&1: 8 slots A + 8 slots B, 4KB (8 rows) per slot
#define STAGE_J(jj)                                                          \
  {                                                                          \
    const bf16_t* Aj = C1 + (size_t)(jj)*524288 + (size_t)n0 * 256;          \
    const bf16_t* Bj = Wf + (size_t)(jj)*65536 + (size_t)h0 * 256;           \
    bf16_t* da = sm + ((jj)&1) * 32768;                                      \
    bf16_t* db = da + 16384;                                                 \
    _Pragma("unroll") for (int s = 0; s < 8; s++) {                          \
      async_cp16(Aj + (size_t)(s * 8 + srow) * 256 + sc8, da + s * 2048 + lbase); \
      async_cp16(Bj + (size_t)(s * 8 + srow) * 256 + sc8, db + s * 2048 + lbase); \
    }                                                                        \
  }

  const float CKJ[5][5] = {  // CKJ[j][k]: coeff of C2_j in out_k (symmetric)
      {1.f, 1.f, 1.f, 1.f, 1.f},
      {1.f, R2C, 0.f, -R2C, -1.f},
      {1.f, 0.f, -1.f, 0.f, 1.f},
      {1.f, -R2C, 0.f, R2C, -1.f},
      {1.f, -1.f, 1.f, -1.f, 1.f}};

  f32x4 outk[5][2][2] = {};

  STAGE_J(0);
#pragma unroll
  for (int j = 0; j < 5; j++) {
    if (j < 4) {
      STAGE_J(j + 1);
      __builtin_amdgcn_s_waitcnt(0x4F70);  // vmcnt(16): tile j landed
    } else {
      __builtin_amdgcn_s_waitcnt(0xF70);   // vmcnt(0)
    }
    __builtin_amdgcn_s_barrier();
    const bf16_t* Ab = sm + (j & 1) * 32768;
    const bf16_t* Bb = Ab + 16384;
    f32x4 acc[2][2] = {};
#pragma unroll
    for (int kh = 0; kh < 8; kh++) {
      int c16 = kh * 4 + quad;
      int cb = (c16 & ~7) << 3;
      bf16x8 af[2], bfr[2];
#pragma unroll
      for (int i = 0; i < 2; i++) {
        int ra = wn + i * 16 + l16;
        int rb = wh + i * 16 + l16;
        af[i] = *(const bf16x8*)(Ab + ra * 256 + cb + (((c16 & 7) ^ (ra & 7)) << 3));
        bfr[i] = *(const bf16x8*)(Bb + rb * 256 + cb + (((c16 & 7) ^ (rb & 7)) << 3));
      }
#pragma unroll
      for (int i = 0; i < 2; i++)
#pragma unroll
        for (int t = 0; t < 2; t++)
          acc[i][t] = __builtin_amdgcn_mfma_f32_16x16x32_bf16(af[i], bfr[t],
                                                              acc[i][t], 0, 0, 0);
    }
#pragma unroll
    for (int k = 0; k < 5; k++) {
      if (CKJ[j][k] != 0.f) {
#pragma unroll
        for (int i = 0; i < 2; i++)
#pragma unroll
          for (int t = 0; t < 2; t++)
#pragma unroll
            for (int rg = 0; rg < 4; rg++)
              outk[k][i][t][rg] += CKJ[j][k] * acc[i][t][rg];
      }
    }
    __builtin_amdgcn_s_barrier();  // buffer (j+1)&1 reads done before re-stage
  }

  // write out[n][h][0..7]; C/D layout col=lane&15, row=quad*4+reg
#pragma unroll
  for (int i = 0; i < 2; i++) {
#pragma unroll
    for (int rg = 0; rg < 4; rg++) {
      int n = n0 + wn + i * 16 + quad * 4 + rg;
#pragma unroll
      for (int t = 0; t < 2; t++) {
        int h = h0 + wh + t * 16 + l16;
        float c0 = outk[0][i][t][rg], c1 = outk[1][i][t][rg];
        float c2 = outk[2][i][t][rg], c3 = outk[3][i][t][rg];
        float c4 = outk[4][i][t][rg];
        float4* op = (float4*)(out + (size_t)n * 2048 + h * 8);
        op[0] = make_float4(c0, c1, c2, c3);
        op[1] = make_float4(c4, c3, c2, c1);
      }
    }
  }
#undef STAGE_J
}

extern "C" void kernel_launch(void* const* d_in, const int* in_sizes, int n_in,
                              void* d_out, int out_size, void* d_ws, size_t ws_size,
                              hipStream_t stream) {
  const float* X = (const float*)d_in[0];   // (2048,256,8)
  const float* A = (const float*)d_in[1];   // (2048,2048,8)
  const float* W = (const float*)d_in[2];   // (256,256,8)
  float* out = (float*)d_out;               // (2048,256,8)
  char* ws = (char*)d_ws;

  bf16_t* Af  = (bf16_t*)(ws);              // 5*2048*2048*2 = 41943040
  bf16_t* Xft = (bf16_t*)(ws + 41943040);   // 5*256*2048*2  =  5242880
  bf16_t* Wft = (bf16_t*)(ws + 47185920);   // 5*256*256*2   =   655360
  bf16_t* C1  = (bf16_t*)(ws + 47841280);   // 5*2048*256*2  =  5242880
                                            // total 53084160 B

  k_pre<<<dim3(2560), 256, 0, stream>>>(X, A, W, Xft, Af, Wft);
  gemm_ring<<<dim3(16, 2, 5), 256, 0, stream>>>(
      Af, Xft, C1, 2048, (size_t)4194304, (size_t)524288, (size_t)524288);
  gemm_fc<<<dim3(32, 4), 256, 0, stream>>>(C1, Wft, out);
}